// Round 2
// baseline (357.856 us; speedup 1.0000x reference)
//
#include <hip/hip_runtime.h>
#include <hip/hip_bf16.h>
#include <stdint.h>

typedef __hip_bfloat16 bf16;
typedef __bf16 bf16x8 __attribute__((ext_vector_type(8)));
typedef float f32x4 __attribute__((ext_vector_type(4)));

#define B_ 2
#define T_ 2048
#define HID_ 2048
#define H_ 16
#define D_ 128
#define WIN_ 512

// ---- async global->LDS, 16B per lane (lds dest = wave-uniform base + lane*16) ----
__device__ __forceinline__ void async_copy16(const void* g, void* l) {
  __builtin_amdgcn_global_load_lds(
      (__attribute__((address_space(1))) void*)(uintptr_t)g,
      (__attribute__((address_space(3))) void*)(uint32_t)(uintptr_t)l,
      16, 0, 0);
}

// raw workgroup barrier with compiler memory fences (no vmcnt/lgkm drain)
__device__ __forceinline__ void block_sync() {
  asm volatile("" ::: "memory");
  __builtin_amdgcn_s_barrier();
  asm volatile("" ::: "memory");
}

// =================== fused fp32->bf16 (h and w1 in one launch) ===================
__global__ __launch_bounds__(256) void cvt4_all(
    const float* __restrict__ h, const float* __restrict__ w1, bf16* __restrict__ outh, bf16* __restrict__ outw1)
{
  int i = blockIdx.x * 256 + threadIdx.x;
  const int NH = 2097152;            // h: 2*2048*2048 /4
  const float* in; bf16* out;
  if (i < NH) { in = h; out = outh; }
  else { i -= NH; in = w1; out = outw1; }   // w1: 4*512*2048 /4 = 1048576
  const float4 v = ((const float4*)in)[i];
  bf16* p = out + (size_t)i * 4;
  p[0] = __float2bfloat16(v.x);
  p[1] = __float2bfloat16(v.y);
  p[2] = __float2bfloat16(v.z);
  p[3] = __float2bfloat16(v.w);
}

// =================== fused fp32->bf16 + transpose, 4 weight matrices in one launch ===================
// out[C][R] = bf16(in[R][C]^T). Ranges: wq_comp(1024 blk), wk(256), wv(256), wq_up(1024).
__global__ __launch_bounds__(256) void cvtT_all(
    const float* __restrict__ wqc, const float* __restrict__ wk, const float* __restrict__ wv,
    const float* __restrict__ wqu, bf16* __restrict__ qkvT, bf16* __restrict__ wquT)
{
  __shared__ bf16 tile[32][33];
  const int id = blockIdx.x;
  const float* in; bf16* out; int R, C, bx, by;
  if (id < 1024)      { int l = id;        in = wqc; out = qkvT;                      R = 2048; C = 512;  bx = (l & 15) * 32; by = (l >> 4) * 32; }
  else if (id < 1280) { int l = id - 1024; in = wk;  out = qkvT + (size_t)512 * 2048; R = 2048; C = 128;  bx = (l & 3) * 32;  by = (l >> 2) * 32; }
  else if (id < 1536) { int l = id - 1280; in = wv;  out = qkvT + (size_t)640 * 2048; R = 2048; C = 128;  bx = (l & 3) * 32;  by = (l >> 2) * 32; }
  else                { int l = id - 1536; in = wqu; out = wquT;                      R = 512;  C = 2048; bx = (l & 63) * 32; by = (l >> 6) * 32; }
  const int tx = threadIdx.x & 31, ty = threadIdx.x >> 5;
#pragma unroll
  for (int i = 0; i < 32; i += 8)
    tile[ty+i][tx] = __float2bfloat16(in[(size_t)(by + ty + i)*C + bx + tx]);
  __syncthreads();
#pragma unroll
  for (int i = 0; i < 32; i += 8)
    out[(size_t)(bx + ty + i)*R + by + tx] = tile[tx][ty+i];
}

// =================== single fp32->bf16 transpose (w2) ===================
__global__ __launch_bounds__(256) void cvtT(
    const float* __restrict__ in, bf16* __restrict__ out, int R, int C)
{
  __shared__ bf16 tile[32][33];
  const int bx = blockIdx.x*32, by = blockIdx.y*32;
  const int tx = threadIdx.x & 31, ty = threadIdx.x >> 5;
#pragma unroll
  for (int i = 0; i < 32; i += 8)
    tile[ty+i][tx] = __float2bfloat16(in[(size_t)(by + ty + i)*C + bx + tx]);
  __syncthreads();
#pragma unroll
  for (int i = 0; i < 32; i += 8)
    out[(size_t)(bx + ty + i)*R + by + tx] = tile[tx][ty+i];
}

// =================== bf16 transpose: out[C][R] = in[R][C]^T (batched via z) ===================
__global__ __launch_bounds__(256) void transpose_k(
    const bf16* __restrict__ in, bf16* __restrict__ out,
    int R, int C, int ldin, int ldout, long long inBatch, long long outBatch)
{
  __shared__ bf16 tile[32][33];
  in  += (size_t)blockIdx.z * inBatch;
  out += (size_t)blockIdx.z * outBatch;
  const int bx = blockIdx.x*32, by = blockIdx.y*32;
  const int tx = threadIdx.x & 31, ty = threadIdx.x >> 5;
#pragma unroll
  for (int i = 0; i < 32; i += 8)
    tile[ty+i][tx] = in[(size_t)(by + ty + i)*ldin + bx + tx];
  __syncthreads();
#pragma unroll
  for (int i = 0; i < 32; i += 8)
    out[(size_t)(bx + ty + i)*ldout + by + tx] = tile[tx][ty+i];
}

// =================== bf16 GEMM (m97 structure): C[M,N] = A[M,K] * BT[N,K]^T ===================
// kept for the qkv GEMM (N=768 -> 192 blocks; 256x128 tiling would under-occupy)
template <bool F32OUT>
__global__ __launch_bounds__(256) void gemm_bt(
    const bf16* __restrict__ Ab, const bf16* __restrict__ Bb, void* __restrict__ Cb,
    int K, int lda, int ldb, int ldc,
    long long sAz, long long sBz, long long sCz)
{
  const bf16* A = Ab + (size_t)blockIdx.z * sAz;
  const bf16* B = Bb + (size_t)blockIdx.z * sBz;
  __shared__ __align__(16) __bf16 sa[128*64];
  __shared__ __align__(16) __bf16 sb[128*64];
  const int bm = blockIdx.x * 128, bn = blockIdx.y * 128;
  const int t = threadIdx.x;
  const int wave = t >> 6, lane = t & 63;
  const int fm = lane & 15, quad = lane >> 4;
  const int wm = (wave & 1) * 64, wn = (wave >> 1) * 64;
  const int arow0 = t >> 3;
  const int acol_sw = (((t & 7) ^ (arow0 & 7)) << 3);
  const int fsw = fm & 7;

  f32x4 acc[4][4];
#pragma unroll
  for (int i = 0; i < 4; ++i)
#pragma unroll
    for (int j = 0; j < 4; ++j) acc[i][j] = {0.f, 0.f, 0.f, 0.f};

  for (int k0 = 0; k0 < K; k0 += 64) {
    __syncthreads();
#pragma unroll
    for (int i = 0; i < 4; ++i)
      async_copy16(&A[(size_t)(bm + arow0 + i*32)*lda + k0 + acol_sw], &sa[(size_t)(i*256 + wave*64)*8]);
#pragma unroll
    for (int i = 0; i < 4; ++i)
      async_copy16(&B[(size_t)(bn + arow0 + i*32)*ldb + k0 + acol_sw], &sb[(size_t)(i*256 + wave*64)*8]);
    __syncthreads();
#pragma unroll
    for (int ks = 0; ks < 64; ks += 32) {
      bf16x8 av[4], bv[4];
#pragma unroll
      for (int mt = 0; mt < 4; ++mt)
        av[mt] = *(const bf16x8*)&sa[(wm + mt*16 + fm)*64 + ((((ks>>3) + quad) ^ fsw) << 3)];
#pragma unroll
      for (int nt = 0; nt < 4; ++nt)
        bv[nt] = *(const bf16x8*)&sb[(wn + nt*16 + fm)*64 + ((((ks>>3) + quad) ^ fsw) << 3)];
#pragma unroll
      for (int mt = 0; mt < 4; ++mt)
#pragma unroll
        for (int nt = 0; nt < 4; ++nt)
          acc[mt][nt] = __builtin_amdgcn_mfma_f32_16x16x32_bf16(av[mt], bv[nt], acc[mt][nt], 0, 0, 0);
    }
  }
  if constexpr (F32OUT) {
    float* C = (float*)Cb + (size_t)blockIdx.z * sCz;
#pragma unroll
    for (int mt = 0; mt < 4; ++mt)
#pragma unroll
      for (int r = 0; r < 4; ++r) {
        const int row = bm + wm + mt*16 + quad*4 + r;
#pragma unroll
        for (int nt = 0; nt < 4; ++nt)
          C[(size_t)row*ldc + bn + wn + nt*16 + fm] = acc[mt][nt][r];
      }
  } else {
    bf16* C = (bf16*)Cb + (size_t)blockIdx.z * sCz;
#pragma unroll
    for (int mt = 0; mt < 4; ++mt)
#pragma unroll
      for (int r = 0; r < 4; ++r) {
        const int row = bm + wm + mt*16 + quad*4 + r;
#pragma unroll
        for (int nt = 0; nt < 4; ++nt)
          C[(size_t)row*ldc + bn + wn + nt*16 + fm] = __float2bfloat16(acc[mt][nt][r]);
      }
  }
}

// =================== 8-phase pipelined GEMM: C[M,N] = A[M,K] * BT[N,K]^T ===================
// BM=256, BN=128, BK=64; 512 threads = 8 waves. Counted vmcnt(2) once per K-tile (T3+T4),
// setprio around MFMA cluster (T5), XOR-swizzled LDS (T2). See round-0 notes for hazard proof.
template <bool F32OUT>
__global__ __launch_bounds__(512, 2) void gemm_bt8(
    const bf16* __restrict__ Ab, const bf16* __restrict__ Bb, void* __restrict__ Cb,
    int K, int lda, int ldb, int ldc,
    long long sAz, long long sBz, long long sCz)
{
  const bf16* A = Ab + (size_t)blockIdx.z * sAz;
  const bf16* B = Bb + (size_t)blockIdx.z * sBz;
  __shared__ __align__(16) __bf16 sA[2][256*64];
  __shared__ __align__(16) __bf16 sB[2][128*64];
  const int bm = blockIdx.x * 256, bn = blockIdx.y * 128;
  const int t = threadIdx.x;
  const int wave = t >> 6, lane = t & 63;
  const int fm = lane & 15, quad = lane >> 4, fsw = fm & 7;
  const int wave_m = wave >> 1, wave_n = wave & 1;
  const int srow = t >> 3;                      // staging row within a 64-row granule
  const int cchunk = (t & 7) ^ (srow & 7);      // pre-swizzled source chunk (inverse of read XOR)
  const int NT = K >> 6;                        // number of K-tiles (NT >= 2 required)

  auto stage = [&](int tile, int o) {           // o: 0=Bh0 1=Bh1 2=Ah0 3=Ah1
    if (tile >= NT) return;
    const int par = tile & 1;
    const int kc = (tile << 6) + (cchunk << 3);
    if (o < 2) {
      async_copy16(&B[(size_t)(bn + (o << 6) + srow)*ldb + kc],
                   &sB[par][(size_t)((o << 6) + wave*8) * 64]);
    } else {
      const int h = (o - 2) << 7;
      async_copy16(&A[(size_t)(bm + h + srow)*lda + kc],
                   &sA[par][(size_t)(h + wave*8) * 64]);
      async_copy16(&A[(size_t)(bm + h + 64 + srow)*lda + kc],
                   &sA[par][(size_t)(h + 64 + wave*8) * 64]);
    }
  };

  f32x4 acc[4][4];
#pragma unroll
  for (int i = 0; i < 4; ++i)
#pragma unroll
    for (int j = 0; j < 4; ++j) acc[i][j] = {0.f, 0.f, 0.f, 0.f};

  // prologue: tile0 {Bh0,Bh1,Ah0,Ah1} + tile1 {Bh0,Bh1} = 8 loads; allow tile1's B (2) in flight
  stage(0, 0); stage(0, 1); stage(0, 2); stage(0, 3);
  stage(1, 0); stage(1, 1);
  asm volatile("s_waitcnt vmcnt(2)" ::: "memory");
  block_sync();

  for (int d = 0; d < NT; ++d) {
    const int par = d & 1;
    bf16x8 bfr[4][2];
#pragma unroll
    for (int q = 0; q < 4; ++q) {
      const int arow = wave_m*64 + q*16 + fm;
      const bf16x8 a0 = *(const bf16x8*)&sA[par][(size_t)arow*64 + ((quad ^ fsw) << 3)];
      const bf16x8 a1 = *(const bf16x8*)&sA[par][(size_t)arow*64 + (((4 + quad) ^ fsw) << 3)];
      if (q == 0) {
#pragma unroll
        for (int n = 0; n < 4; ++n) {
          const int brow = wave_n*64 + n*16 + fm;
          bfr[n][0] = *(const bf16x8*)&sB[par][(size_t)brow*64 + ((quad ^ fsw) << 3)];
          bfr[n][1] = *(const bf16x8*)&sB[par][(size_t)brow*64 + (((4 + quad) ^ fsw) << 3)];
        }
      }
      if (q == 0)      stage(d + 1, 2);
      else if (q == 1) stage(d + 1, 3);
      else if (q == 2) stage(d + 2, 0);
      else             stage(d + 2, 1);
      block_sync();
      __builtin_amdgcn_s_setprio(1);
#pragma unroll
      for (int n = 0; n < 4; ++n)
        acc[q][n] = __builtin_amdgcn_mfma_f32_16x16x32_bf16(a0, bfr[n][0], acc[q][n], 0, 0, 0);
#pragma unroll
      for (int n = 0; n < 4; ++n)
        acc[q][n] = __builtin_amdgcn_mfma_f32_16x16x32_bf16(a1, bfr[n][1], acc[q][n], 0, 0, 0);
      __builtin_amdgcn_s_setprio(0);
      if (q == 3 && d < NT - 1) {           // per-K-tile checkpoint guarding tile d+1
        if (d == NT - 2) asm volatile("s_waitcnt vmcnt(0)" ::: "memory");
        else             asm volatile("s_waitcnt vmcnt(2)" ::: "memory");
      }
      block_sync();
    }
  }

  if constexpr (F32OUT) {
    float* C = (float*)Cb + (size_t)blockIdx.z * sCz;
#pragma unroll
    for (int q = 0; q < 4; ++q)
#pragma unroll
      for (int r = 0; r < 4; ++r) {
        const int row = bm + wave_m*64 + q*16 + quad*4 + r;
#pragma unroll
        for (int n = 0; n < 4; ++n)
          C[(size_t)row*ldc + bn + wave_n*64 + n*16 + fm] = acc[q][n][r];
      }
  } else {
    bf16* C = (bf16*)Cb + (size_t)blockIdx.z * sCz;
#pragma unroll
    for (int q = 0; q < 4; ++q)
#pragma unroll
      for (int r = 0; r < 4; ++r) {
        const int row = bm + wave_m*64 + q*16 + quad*4 + r;
#pragma unroll
        for (int n = 0; n < 4; ++n)
          C[(size_t)row*ldc + bn + wave_n*64 + n*16 + fm] = __float2bfloat16(acc[q][n][r]);
      }
  }
}

// =================== fused partial-RoPE + RMSNorm, q and k paths in one launch ===================
__global__ __launch_bounds__(256) void rope_rms_all(
    const bf16* __restrict__ qin, bf16* __restrict__ qout, const float* __restrict__ qw,
    const bf16* __restrict__ kin, bf16* __restrict__ kout, const float* __restrict__ kw)
{
  int blk = blockIdx.x;
  const bf16* in; bf16* out; const float* w; int in_stride, t_shift; float oscale;
  if (blk < 16384) { in = qin; out = qout; w = qw; in_stride = 128; t_shift = 4; oscale = 0.12751744f; }
  else { blk -= 16384; in = kin; out = kout; w = kw; in_stride = 768; t_shift = 0; oscale = 1.0f; }
  const int rid = blk*4 + (threadIdx.x >> 6);
  const int lane = threadIdx.x & 63;
  const bf16* row = in + (size_t)rid * in_stride;
  float e0 = __bfloat162float(row[lane]);
  float e1 = __bfloat162float(row[lane + 64]);
  float s2 = e0*e0 + e1*e1;
#pragma unroll
  for (int off = 32; off; off >>= 1) s2 += __shfl_xor(s2, off);
  const float rms = rsqrtf(s2 * (1.f/128.f) + 1e-6f) * oscale;
  const int tpos = (rid >> t_shift) & (T_ - 1);
  const int i = lane & 31;
  const float inv = expf(-(float)i * 0.28782313662425574f);  // ln(10000)/32
  const float ang = (float)tpos * inv;
  float sn, c;
  sincosf(ang, &sn, &c);
  const float other = __shfl_xor(e0, 32);
  const float r0 = (lane < 32) ? (e0*c - other*sn) : (other*sn + e0*c);
  bf16* orow = out + (size_t)rid * 128;
  orow[lane]      = __float2bfloat16(r0 * rms * w[lane]);
  orow[lane + 64] = __float2bfloat16(e1 * rms * w[lane + 64]);
}

// =================== sliding-window flash attention (MQA, sink, max-free, swizzled LDS) ===================
// T14 async-STAGE split: K/V for tile kt+1 are global_load'ed into regs right after tile kt's
// post-write barrier (in flight across the whole compute phase AND the next loop-top raw
// barrier), then ds_write'd once readers of tile kt are done. The loop-top barrier is a raw
// s_barrier (no vmcnt drain -- VGPR loads have no cross-thread visibility); the compiler
// inserts the precise counted vmcnt wait at the ds_write that consumes the regs.
__global__ __launch_bounds__(256) void attn_kernel(
    const bf16* __restrict__ q,     // [B,T,H*D]  (pre-scaled by 1/(sqrt(D)ln2))
    const bf16* __restrict__ k,     // [B,T,D]
    const bf16* __restrict__ vt,    // [B,D,T]
    const float* __restrict__ sink, // [H]
    bf16* __restrict__ o)           // [B,T,H*D]
{
  __shared__ __align__(16) __bf16 sQ[64*128];   // 16 chunk-slots/row, swizzled ^(r&7)
  __shared__ __align__(16) __bf16 sK[64*128];
  __shared__ __align__(16) __bf16 sV[128*64];   // [d][s], 8 slots/row, swizzled ^(d&7)
  __shared__ __align__(16) __bf16 sP[64*72];    // stride 72: 2-way max, no swizzle
  const int qt = blockIdx.x, h = blockIdx.y, b = blockIdx.z;
  const int qb = qt * 64;
  const int t = threadIdx.x, wave = t >> 6, lane = t & 63;
  const int fm = lane & 15, quad = lane >> 4;
  const int fsw = fm & 7;
  const int qw = qb + wave*16;

#pragma unroll
  for (int i = 0; i < 4; ++i) {   // stage Q once (async, source-swizzled)
    int chunk = i*256 + t;
    int r = chunk >> 4, c8 = (chunk & 15) ^ (r & 7);
    async_copy16(&q[(size_t)((b*T_ + qb + r)*H_ + h)*D_ + c8*8], &sQ[(size_t)(i*256 + wave*64)*8]);
  }

  bf16x8 kreg[4], vreg[4];
  auto load_kv = [&](int kb) {     // source-swizzled (same layout the DMA produced)
#pragma unroll
    for (int i = 0; i < 4; ++i) {
      int chunk = i*256 + t;
      int r = chunk >> 4, c8 = (chunk & 15) ^ (r & 7);
      kreg[i] = *(const bf16x8*)&k[(size_t)(b*T_ + kb + r)*D_ + c8*8];
    }
#pragma unroll
    for (int i = 0; i < 4; ++i) {
      int chunk = i*256 + t;
      int d = chunk >> 3, c8 = (chunk & 7) ^ (d & 7);
      vreg[i] = *(const bf16x8*)&vt[(size_t)(b*D_ + d)*T_ + kb + c8*8];
    }
  };

  float l_run[4] = {0.f, 0.f, 0.f, 0.f};
  f32x4 oacc[8];
#pragma unroll
  for (int i = 0; i < 8; ++i) oacc[i] = {0.f, 0.f, 0.f, 0.f};

  int lo = qb - (WIN_ - 1); if (lo < 0) lo = 0;
  const int kt0 = lo >> 6;
  load_kv(kt0 * 64);              // prologue prefetch (in flight across first barrier)

  for (int kt = kt0; kt <= qt; ++kt) {
    const int kb = kt * 64;
    block_sync();                 // readers of previous tile done (raw: no vmcnt drain)
#pragma unroll
    for (int i = 0; i < 4; ++i)   // compiler inserts counted vmcnt wait for kreg here
      *(bf16x8*)&sK[(size_t)(i*256 + t)*8] = kreg[i];
#pragma unroll
    for (int i = 0; i < 4; ++i)
      *(bf16x8*)&sV[(size_t)(i*256 + t)*8] = vreg[i];
    __syncthreads();              // writes visible; vmcnt already 0 here (except Q, 1st iter)
    if (kt < qt) load_kv(kb + 64);  // prefetch next tile under QK+softmax+PV

    // S strip (16 q-rows x 64 k-cols per wave) = Q K^T  (log2-units)
    f32x4 s[4];
#pragma unroll
    for (int nt = 0; nt < 4; ++nt) s[nt] = {0.f, 0.f, 0.f, 0.f};
#pragma unroll
    for (int ds = 0; ds < 4; ++ds) {
      bf16x8 aq = *(const bf16x8*)&sQ[(wave*16 + fm)*128 + (((ds*4 + quad) ^ fsw) << 3)];
#pragma unroll
      for (int nt = 0; nt < 4; ++nt) {
        bf16x8 bk = *(const bf16x8*)&sK[(nt*16 + fm)*128 + (((ds*4 + quad) ^ fsw) << 3)];
        s[nt] = __builtin_amdgcn_mfma_f32_16x16x32_bf16(aq, bk, s[nt], 0, 0, 0);
      }
    }
    const bool interior = (kb + 63 <= qw) && (kb >= qw - (WIN_ - 16));
    if (!interior) {
      const int qi0 = qb + wave*16 + quad*4;
#pragma unroll
      for (int nt = 0; nt < 4; ++nt) {
        const int ki = kb + nt*16 + fm;
#pragma unroll
        for (int r = 0; r < 4; ++r) {
          const int qi = qi0 + r;
          const bool ok = (ki <= qi) && (qi - ki < WIN_);
          s[nt][r] = ok ? s[nt][r] : -1e30f;
        }
      }
    }
#pragma unroll
    for (int nt = 0; nt < 4; ++nt)
#pragma unroll
      for (int r = 0; r < 4; ++r) {
        const float p = __builtin_exp2f(s[nt][r]);
        l_run[r] += p;
        sP[(wave*16 + quad*4 + r)*72 + nt*16 + fm] = __float2bfloat16(p);
      }
    asm volatile("s_waitcnt lgkmcnt(0)" ::: "memory");
    // O += P V
#pragma unroll
    for (int ks = 0; ks < 2; ++ks) {
      bf16x8 ap = *(const bf16x8*)&sP[(wave*16 + fm)*72 + ks*32 + quad*8];
#pragma unroll
      for (int nt = 0; nt < 8; ++nt) {
        bf16x8 bv = *(const bf16x8*)&sV[(nt*16 + fm)*64 + (((ks*4 + quad) ^ fsw) << 3)];
        oacc[nt] = __builtin_amdgcn_mfma_f32_16x16x32_bf16(ap, bv, oacc[nt], 0, 0, 0);
      }
    }
  }
#pragma unroll
  for (int off = 1; off < 16; off <<= 1)
#pragma unroll
    for (int r = 0; r < 4; ++r) l_run[r] += __shfl_xor(l_run[r], off);
  const float sink_p = __builtin_exp2f(sink[h] * 1.4426950408889634f);
#pragma unroll
  for (int r = 0; r < 4; ++r) {
    const int qi = qb + wave*16 + quad*4 + r;
    const float inv_l = 1.f / (l_run[r] + sink_p);
#pragma unroll
    for (int nt = 0; nt < 8; ++nt) {
      const int d = nt*16 + fm;
      o[(size_t)(b*T_ + qi)*(H_*D_) + h*D_ + d] = __float2bfloat16(oacc[nt][r] * inv_l);
    }
  }
}

// =========================================================================================
extern "C" void kernel_launch(void* const* d_in, const int* in_sizes, int n_in,
                              void* d_out, int out_size, void* d_ws, size_t ws_size,
                              hipStream_t stream) {
  (void)in_sizes; (void)n_in; (void)out_size; (void)ws_size;
  const float* h       = (const float*)d_in[0];
  const float* wq_comp = (const float*)d_in[1];
  const float* wq_up   = (const float*)d_in[2];
  const float* wk      = (const float*)d_in[3];
  const float* wv      = (const float*)d_in[4];
  const float* qnw     = (const float*)d_in[5];
  const float* knw     = (const float*)d_in[6];
  const float* sink    = (const float*)d_in[7];
  const float* w1      = (const float*)d_in[8];
  const float* w2      = (const float*)d_in[9];
  float* out = (float*)d_out;
  bf16* ws   = (bf16*)d_ws;

  // ---- overlaid workspace (bf16 element offsets; peak 35.5M elems = 71 MB) ----
  const size_t M1 = 1048576;
  const size_t o_hb    = 0;               // [4096][2048] ph1-3
  const size_t o_qr    = 8*M1;            // [4096][2048] ph2-4
  const size_t o_w2T   = 0;               // [2048][8192] ph5 (hb,qr dead)
  const size_t o_qkv   = 16*M1;           // [4096][768]  ph2-3 (qc|k|v)
  const size_t o_WefT  = 16*M1;           // [2048][2048] ph5 (qkv dead)
  const size_t o_krt   = 20*M1;           // [4096][128]  ph3-4
  const size_t o_vt    = 20*M1 + 524288;  // [2][128][2048] ph3-4
  const size_t o_wqkvT = 21*M1;           // [768][2048]  ph1-3 (wqcT;wkT;wvT stacked)
  const size_t o_wquT  = 22*M1 + 524288;  // [2048][512]  ph1-2
  const size_t o_w1b   = 23*M1 + 524288;  // [4][512][2048] ph1-5
  const size_t o_x     = 27*M1 + 524288;  // [4096][2048] ph4-5

  const dim3 tb(256);
  // ---- ph1: conversions (merged: 2 launches) ----
  cvt4_all<<<dim3(12288), tb, 0, stream>>>(h, w1, ws+o_hb, ws+o_w1b);
  cvtT_all<<<dim3(2560), tb, 0, stream>>>(wq_comp, wk, wv, wq_up, ws+o_wqkvT, ws+o_wquT);

  // ---- ph2/3: [qc|k|v] = h @ [wqc|wk|wv] in ONE N=768 GEMM (m97 structure) ----
  gemm_bt<false><<<dim3(32, 6), tb, 0, stream>>>(ws+o_hb, ws+o_wqkvT, ws+o_qkv,
                                                 2048, 2048, 2048, 768, 0, 0, 0);
  // q = qc @ wq_up  (8-phase 256x128 pipeline)
  gemm_bt8<false><<<dim3(16, 16), dim3(512), 0, stream>>>(ws+o_qkv, ws+o_wquT, ws+o_qr,
                                                          512, 768, 512, 2048, 0, 0, 0);
  // rope+rms q (pre-scaled by 1/(sqrt(D)ln2)) and k in one launch
  rope_rms_all<<<dim3(17408), tb, 0, stream>>>(ws+o_qr, ws+o_qr, qnw,
                                               ws+o_qkv + 512, ws+o_krt, knw);
  // transpose v -> vt
  transpose_k<<<dim3(4, 64, 2), tb, 0, stream>>>(ws+o_qkv + 640, ws+o_vt, 2048, 128, 768, 2048,
                                                 (long long)2048*768, (long long)128*2048);

  // ---- ph4: attention ----
  attn_kernel<<<dim3(T_/64, H_, B_), tb, 0, stream>>>(ws+o_qr, ws+o_krt, ws+o_vt, sink, ws+o_x);

  // ---- ph5: WeffT = w2T_g @ w1_g^T per group (z=g), then out = x @ WeffT^T ----
  cvtT<<<dim3(64, 256), tb, 0, stream>>>(w2, ws+o_w2T, 8192, 2048);
  gemm_bt8<false><<<dim3(8, 4, 4), dim3(512), 0, stream>>>(ws+o_w2T, ws+o_w1b, ws+o_WefT,
                                                           2048, 8192, 2048, 2048,
                                                           2048, (long long)512*2048, 512);
  gemm_bt8<true><<<dim3(16, 16), dim3(512), 0, stream>>>(ws+o_x, ws+o_WefT, out,
                                                         2048, 2048, 2048, 2048, 0, 0, 0);
}

// Round 3
// 354.423 us; speedup vs baseline: 1.0097x; 1.0097x over previous
//
#include <hip/hip_runtime.h>
#include <hip/hip_bf16.h>
#include <stdint.h>

typedef __hip_bfloat16 bf16;
typedef __bf16 bf16x8 __attribute__((ext_vector_type(8)));
typedef float f32x4 __attribute__((ext_vector_type(4)));

#define B_ 2
#define T_ 2048
#define HID_ 2048
#define H_ 16
#define D_ 128
#define WIN_ 512

// ---- async global->LDS, 16B per lane (lds dest = wave-uniform base + lane*16) ----
__device__ __forceinline__ void async_copy16(const void* g, void* l) {
  __builtin_amdgcn_global_load_lds(
      (__attribute__((address_space(1))) void*)(uintptr_t)g,
      (__attribute__((address_space(3))) void*)(uint32_t)(uintptr_t)l,
      16, 0, 0);
}

// raw workgroup barrier with compiler memory fences (no vmcnt/lgkm drain)
__device__ __forceinline__ void block_sync() {
  asm volatile("" ::: "memory");
  __builtin_amdgcn_s_barrier();
  asm volatile("" ::: "memory");
}

// =================== fused fp32->bf16 (h and w1 in one launch) ===================
__global__ __launch_bounds__(256) void cvt4_all(
    const float* __restrict__ h, const float* __restrict__ w1, bf16* __restrict__ outh, bf16* __restrict__ outw1)
{
  int i = blockIdx.x * 256 + threadIdx.x;
  const int NH = 2097152;            // h: 2*2048*2048 /4
  const float* in; bf16* out;
  if (i < NH) { in = h; out = outh; }
  else { i -= NH; in = w1; out = outw1; }   // w1: 4*512*2048 /4 = 1048576
  const float4 v = ((const float4*)in)[i];
  bf16* p = out + (size_t)i * 4;
  p[0] = __float2bfloat16(v.x);
  p[1] = __float2bfloat16(v.y);
  p[2] = __float2bfloat16(v.z);
  p[3] = __float2bfloat16(v.w);
}

// =================== fused fp32->bf16 + transpose, 4 weight matrices in one launch ===================
// out[C][R] = bf16(in[R][C]^T). Ranges: wq_comp(1024 blk), wk(256), wv(256), wq_up(1024).
__global__ __launch_bounds__(256) void cvtT_all(
    const float* __restrict__ wqc, const float* __restrict__ wk, const float* __restrict__ wv,
    const float* __restrict__ wqu, bf16* __restrict__ qkvT, bf16* __restrict__ wquT)
{
  __shared__ bf16 tile[32][33];
  const int id = blockIdx.x;
  const float* in; bf16* out; int R, C, bx, by;
  if (id < 1024)      { int l = id;        in = wqc; out = qkvT;                      R = 2048; C = 512;  bx = (l & 15) * 32; by = (l >> 4) * 32; }
  else if (id < 1280) { int l = id - 1024; in = wk;  out = qkvT + (size_t)512 * 2048; R = 2048; C = 128;  bx = (l & 3) * 32;  by = (l >> 2) * 32; }
  else if (id < 1536) { int l = id - 1280; in = wv;  out = qkvT + (size_t)640 * 2048; R = 2048; C = 128;  bx = (l & 3) * 32;  by = (l >> 2) * 32; }
  else                { int l = id - 1536; in = wqu; out = wquT;                      R = 512;  C = 2048; bx = (l & 63) * 32; by = (l >> 6) * 32; }
  const int tx = threadIdx.x & 31, ty = threadIdx.x >> 5;
#pragma unroll
  for (int i = 0; i < 32; i += 8)
    tile[ty+i][tx] = __float2bfloat16(in[(size_t)(by + ty + i)*C + bx + tx]);
  __syncthreads();
#pragma unroll
  for (int i = 0; i < 32; i += 8)
    out[(size_t)(bx + ty + i)*R + by + tx] = tile[tx][ty+i];
}

// =================== single fp32->bf16 transpose (w2) ===================
__global__ __launch_bounds__(256) void cvtT(
    const float* __restrict__ in, bf16* __restrict__ out, int R, int C)
{
  __shared__ bf16 tile[32][33];
  const int bx = blockIdx.x*32, by = blockIdx.y*32;
  const int tx = threadIdx.x & 31, ty = threadIdx.x >> 5;
#pragma unroll
  for (int i = 0; i < 32; i += 8)
    tile[ty+i][tx] = __float2bfloat16(in[(size_t)(by + ty + i)*C + bx + tx]);
  __syncthreads();
#pragma unroll
  for (int i = 0; i < 32; i += 8)
    out[(size_t)(bx + ty + i)*R + by + tx] = tile[tx][ty+i];
}

// =================== bf16 transpose: out[C][R] = in[R][C]^T (batched via z) ===================
__global__ __launch_bounds__(256) void transpose_k(
    const bf16* __restrict__ in, bf16* __restrict__ out,
    int R, int C, int ldin, int ldout, long long inBatch, long long outBatch)
{
  __shared__ bf16 tile[32][33];
  in  += (size_t)blockIdx.z * inBatch;
  out += (size_t)blockIdx.z * outBatch;
  const int bx = blockIdx.x*32, by = blockIdx.y*32;
  const int tx = threadIdx.x & 31, ty = threadIdx.x >> 5;
#pragma unroll
  for (int i = 0; i < 32; i += 8)
    tile[ty+i][tx] = in[(size_t)(by + ty + i)*ldin + bx + tx];
  __syncthreads();
#pragma unroll
  for (int i = 0; i < 32; i += 8)
    out[(size_t)(bx + ty + i)*ldout + by + tx] = tile[tx][ty+i];
}

// =================== bf16 GEMM (m97 structure): C[M,N] = A[M,K] * BT[N,K]^T ===================
// kept for the qkv GEMM (N=768 -> 192 blocks; 256x128 tiling would under-occupy)
template <bool F32OUT>
__global__ __launch_bounds__(256) void gemm_bt(
    const bf16* __restrict__ Ab, const bf16* __restrict__ Bb, void* __restrict__ Cb,
    int K, int lda, int ldb, int ldc,
    long long sAz, long long sBz, long long sCz)
{
  const bf16* A = Ab + (size_t)blockIdx.z * sAz;
  const bf16* B = Bb + (size_t)blockIdx.z * sBz;
  __shared__ __align__(16) __bf16 sa[128*64];
  __shared__ __align__(16) __bf16 sb[128*64];
  const int bm = blockIdx.x * 128, bn = blockIdx.y * 128;
  const int t = threadIdx.x;
  const int wave = t >> 6, lane = t & 63;
  const int fm = lane & 15, quad = lane >> 4;
  const int wm = (wave & 1) * 64, wn = (wave >> 1) * 64;
  const int arow0 = t >> 3;
  const int acol_sw = (((t & 7) ^ (arow0 & 7)) << 3);
  const int fsw = fm & 7;

  f32x4 acc[4][4];
#pragma unroll
  for (int i = 0; i < 4; ++i)
#pragma unroll
    for (int j = 0; j < 4; ++j) acc[i][j] = {0.f, 0.f, 0.f, 0.f};

  for (int k0 = 0; k0 < K; k0 += 64) {
    __syncthreads();
#pragma unroll
    for (int i = 0; i < 4; ++i)
      async_copy16(&A[(size_t)(bm + arow0 + i*32)*lda + k0 + acol_sw], &sa[(size_t)(i*256 + wave*64)*8]);
#pragma unroll
    for (int i = 0; i < 4; ++i)
      async_copy16(&B[(size_t)(bn + arow0 + i*32)*ldb + k0 + acol_sw], &sb[(size_t)(i*256 + wave*64)*8]);
    __syncthreads();
#pragma unroll
    for (int ks = 0; ks < 64; ks += 32) {
      bf16x8 av[4], bv[4];
#pragma unroll
      for (int mt = 0; mt < 4; ++mt)
        av[mt] = *(const bf16x8*)&sa[(wm + mt*16 + fm)*64 + ((((ks>>3) + quad) ^ fsw) << 3)];
#pragma unroll
      for (int nt = 0; nt < 4; ++nt)
        bv[nt] = *(const bf16x8*)&sb[(wn + nt*16 + fm)*64 + ((((ks>>3) + quad) ^ fsw) << 3)];
#pragma unroll
      for (int mt = 0; mt < 4; ++mt)
#pragma unroll
        for (int nt = 0; nt < 4; ++nt)
          acc[mt][nt] = __builtin_amdgcn_mfma_f32_16x16x32_bf16(av[mt], bv[nt], acc[mt][nt], 0, 0, 0);
    }
  }
  if constexpr (F32OUT) {
    float* C = (float*)Cb + (size_t)blockIdx.z * sCz;
#pragma unroll
    for (int mt = 0; mt < 4; ++mt)
#pragma unroll
      for (int r = 0; r < 4; ++r) {
        const int row = bm + wm + mt*16 + quad*4 + r;
#pragma unroll
        for (int nt = 0; nt < 4; ++nt)
          C[(size_t)row*ldc + bn + wn + nt*16 + fm] = acc[mt][nt][r];
      }
  } else {
    bf16* C = (bf16*)Cb + (size_t)blockIdx.z * sCz;
#pragma unroll
    for (int mt = 0; mt < 4; ++mt)
#pragma unroll
      for (int r = 0; r < 4; ++r) {
        const int row = bm + wm + mt*16 + quad*4 + r;
#pragma unroll
        for (int nt = 0; nt < 4; ++nt)
          C[(size_t)row*ldc + bn + wn + nt*16 + fm] = __float2bfloat16(acc[mt][nt][r]);
      }
  }
}

// =================== 8-phase pipelined GEMM: C[M,N] = A[M,K] * BT[N,K]^T ===================
// BM=256, BN=128, BK=64; 512 threads = 8 waves. Counted vmcnt(2) once per K-tile (T3+T4),
// setprio around MFMA cluster (T5), XOR-swizzled LDS (T2). See round-0 notes for hazard proof.
template <bool F32OUT>
__global__ __launch_bounds__(512, 2) void gemm_bt8(
    const bf16* __restrict__ Ab, const bf16* __restrict__ Bb, void* __restrict__ Cb,
    int K, int lda, int ldb, int ldc,
    long long sAz, long long sBz, long long sCz)
{
  const bf16* A = Ab + (size_t)blockIdx.z * sAz;
  const bf16* B = Bb + (size_t)blockIdx.z * sBz;
  __shared__ __align__(16) __bf16 sA[2][256*64];
  __shared__ __align__(16) __bf16 sB[2][128*64];
  const int bm = blockIdx.x * 256, bn = blockIdx.y * 128;
  const int t = threadIdx.x;
  const int wave = t >> 6, lane = t & 63;
  const int fm = lane & 15, quad = lane >> 4, fsw = fm & 7;
  const int wave_m = wave >> 1, wave_n = wave & 1;
  const int srow = t >> 3;                      // staging row within a 64-row granule
  const int cchunk = (t & 7) ^ (srow & 7);      // pre-swizzled source chunk (inverse of read XOR)
  const int NT = K >> 6;                        // number of K-tiles (NT >= 2 required)

  auto stage = [&](int tile, int o) {           // o: 0=Bh0 1=Bh1 2=Ah0 3=Ah1
    if (tile >= NT) return;
    const int par = tile & 1;
    const int kc = (tile << 6) + (cchunk << 3);
    if (o < 2) {
      async_copy16(&B[(size_t)(bn + (o << 6) + srow)*ldb + kc],
                   &sB[par][(size_t)((o << 6) + wave*8) * 64]);
    } else {
      const int h = (o - 2) << 7;
      async_copy16(&A[(size_t)(bm + h + srow)*lda + kc],
                   &sA[par][(size_t)(h + wave*8) * 64]);
      async_copy16(&A[(size_t)(bm + h + 64 + srow)*lda + kc],
                   &sA[par][(size_t)(h + 64 + wave*8) * 64]);
    }
  };

  f32x4 acc[4][4];
#pragma unroll
  for (int i = 0; i < 4; ++i)
#pragma unroll
    for (int j = 0; j < 4; ++j) acc[i][j] = {0.f, 0.f, 0.f, 0.f};

  // prologue: tile0 {Bh0,Bh1,Ah0,Ah1} + tile1 {Bh0,Bh1} = 8 loads; allow tile1's B (2) in flight
  stage(0, 0); stage(0, 1); stage(0, 2); stage(0, 3);
  stage(1, 0); stage(1, 1);
  asm volatile("s_waitcnt vmcnt(2)" ::: "memory");
  block_sync();

  for (int d = 0; d < NT; ++d) {
    const int par = d & 1;
    bf16x8 bfr[4][2];
#pragma unroll
    for (int q = 0; q < 4; ++q) {
      const int arow = wave_m*64 + q*16 + fm;
      const bf16x8 a0 = *(const bf16x8*)&sA[par][(size_t)arow*64 + ((quad ^ fsw) << 3)];
      const bf16x8 a1 = *(const bf16x8*)&sA[par][(size_t)arow*64 + (((4 + quad) ^ fsw) << 3)];
      if (q == 0) {
#pragma unroll
        for (int n = 0; n < 4; ++n) {
          const int brow = wave_n*64 + n*16 + fm;
          bfr[n][0] = *(const bf16x8*)&sB[par][(size_t)brow*64 + ((quad ^ fsw) << 3)];
          bfr[n][1] = *(const bf16x8*)&sB[par][(size_t)brow*64 + (((4 + quad) ^ fsw) << 3)];
        }
      }
      if (q == 0)      stage(d + 1, 2);
      else if (q == 1) stage(d + 1, 3);
      else if (q == 2) stage(d + 2, 0);
      else             stage(d + 2, 1);
      block_sync();
      __builtin_amdgcn_s_setprio(1);
#pragma unroll
      for (int n = 0; n < 4; ++n)
        acc[q][n] = __builtin_amdgcn_mfma_f32_16x16x32_bf16(a0, bfr[n][0], acc[q][n], 0, 0, 0);
#pragma unroll
      for (int n = 0; n < 4; ++n)
        acc[q][n] = __builtin_amdgcn_mfma_f32_16x16x32_bf16(a1, bfr[n][1], acc[q][n], 0, 0, 0);
      __builtin_amdgcn_s_setprio(0);
      if (q == 3 && d < NT - 1) {           // per-K-tile checkpoint guarding tile d+1
        if (d == NT - 2) asm volatile("s_waitcnt vmcnt(0)" ::: "memory");
        else             asm volatile("s_waitcnt vmcnt(2)" ::: "memory");
      }
      block_sync();
    }
  }

  if constexpr (F32OUT) {
    float* C = (float*)Cb + (size_t)blockIdx.z * sCz;
#pragma unroll
    for (int q = 0; q < 4; ++q)
#pragma unroll
      for (int r = 0; r < 4; ++r) {
        const int row = bm + wave_m*64 + q*16 + quad*4 + r;
#pragma unroll
        for (int n = 0; n < 4; ++n)
          C[(size_t)row*ldc + bn + wave_n*64 + n*16 + fm] = acc[q][n][r];
      }
  } else {
    bf16* C = (bf16*)Cb + (size_t)blockIdx.z * sCz;
#pragma unroll
    for (int q = 0; q < 4; ++q)
#pragma unroll
      for (int r = 0; r < 4; ++r) {
        const int row = bm + wave_m*64 + q*16 + quad*4 + r;
#pragma unroll
        for (int n = 0; n < 4; ++n)
          C[(size_t)row*ldc + bn + wave_n*64 + n*16 + fm] = __float2bfloat16(acc[q][n][r]);
      }
  }
}

// =================== fused partial-RoPE + RMSNorm, q and k paths in one launch ===================
__global__ __launch_bounds__(256) void rope_rms_all(
    const bf16* __restrict__ qin, bf16* __restrict__ qout, const float* __restrict__ qw,
    const bf16* __restrict__ kin, bf16* __restrict__ kout, const float* __restrict__ kw)
{
  int blk = blockIdx.x;
  const bf16* in; bf16* out; const float* w; int in_stride, t_shift; float oscale;
  if (blk < 16384) { in = qin; out = qout; w = qw; in_stride = 128; t_shift = 4; oscale = 0.12751744f; }
  else { blk -= 16384; in = kin; out = kout; w = kw; in_stride = 768; t_shift = 0; oscale = 1.0f; }
  const int rid = blk*4 + (threadIdx.x >> 6);
  const int lane = threadIdx.x & 63;
  const bf16* row = in + (size_t)rid * in_stride;
  float e0 = __bfloat162float(row[lane]);
  float e1 = __bfloat162float(row[lane + 64]);
  float s2 = e0*e0 + e1*e1;
#pragma unroll
  for (int off = 32; off; off >>= 1) s2 += __shfl_xor(s2, off);
  const float rms = rsqrtf(s2 * (1.f/128.f) + 1e-6f) * oscale;
  const int tpos = (rid >> t_shift) & (T_ - 1);
  const int i = lane & 31;
  const float inv = expf(-(float)i * 0.28782313662425574f);  // ln(10000)/32
  const float ang = (float)tpos * inv;
  float sn, c;
  sincosf(ang, &sn, &c);
  const float other = __shfl_xor(e0, 32);
  const float r0 = (lane < 32) ? (e0*c - other*sn) : (other*sn + e0*c);
  bf16* orow = out + (size_t)rid * 128;
  orow[lane]      = __float2bfloat16(r0 * rms * w[lane]);
  orow[lane + 64] = __float2bfloat16(e1 * rms * w[lane + 64]);
}

// =================== sliding-window flash attention (MQA, sink, max-free, swizzled LDS) ===================
// T14 async-STAGE split (round 1) + P-aliased-into-sK (round 2): sK is dead after QK within a
// tile, so P (4608 of sK's 8192 elems, stride 72) reuses it. Dropping the separate sP buffer
// cuts LDS 58368 -> 49152 B => 3 blocks/CU instead of 2 (+50% TLP for the latency-bound chain).
// New post-QK raw barrier orders all waves' QK reads of sK before P overwrites it; the
// end-of-tile barrier orders all PV reads of the alias before next tile's K ds_writes.
__global__ __launch_bounds__(256, 3) void attn_kernel(
    const bf16* __restrict__ q,     // [B,T,H*D]  (pre-scaled by 1/(sqrt(D)ln2))
    const bf16* __restrict__ k,     // [B,T,D]
    const bf16* __restrict__ vt,    // [B,D,T]
    const float* __restrict__ sink, // [H]
    bf16* __restrict__ o)           // [B,T,H*D]
{
  __shared__ __align__(16) __bf16 sQ[64*128];   // 16 chunk-slots/row, swizzled ^(r&7)
  __shared__ __align__(16) __bf16 sK[64*128];   // post-QK: first 64*72 elems reused as P
  __shared__ __align__(16) __bf16 sV[128*64];   // [d][s], 8 slots/row, swizzled ^(d&7)
  const int qt = blockIdx.x, h = blockIdx.y, b = blockIdx.z;
  const int qb = qt * 64;
  const int t = threadIdx.x, wave = t >> 6, lane = t & 63;
  const int fm = lane & 15, quad = lane >> 4;
  const int fsw = fm & 7;
  const int qw = qb + wave*16;

#pragma unroll
  for (int i = 0; i < 4; ++i) {   // stage Q once (async, source-swizzled)
    int chunk = i*256 + t;
    int r = chunk >> 4, c8 = (chunk & 15) ^ (r & 7);
    async_copy16(&q[(size_t)((b*T_ + qb + r)*H_ + h)*D_ + c8*8], &sQ[(size_t)(i*256 + wave*64)*8]);
  }

  bf16x8 kreg[4], vreg[4];
  auto load_kv = [&](int kb) {     // source-swizzled (same layout the DMA produced)
#pragma unroll
    for (int i = 0; i < 4; ++i) {
      int chunk = i*256 + t;
      int r = chunk >> 4, c8 = (chunk & 15) ^ (r & 7);
      kreg[i] = *(const bf16x8*)&k[(size_t)(b*T_ + kb + r)*D_ + c8*8];
    }
#pragma unroll
    for (int i = 0; i < 4; ++i) {
      int chunk = i*256 + t;
      int d = chunk >> 3, c8 = (chunk & 7) ^ (d & 7);
      vreg[i] = *(const bf16x8*)&vt[(size_t)(b*D_ + d)*T_ + kb + c8*8];
    }
  };

  float l_run[4] = {0.f, 0.f, 0.f, 0.f};
  f32x4 oacc[8];
#pragma unroll
  for (int i = 0; i < 8; ++i) oacc[i] = {0.f, 0.f, 0.f, 0.f};

  int lo = qb - (WIN_ - 1); if (lo < 0) lo = 0;
  const int kt0 = lo >> 6;
  load_kv(kt0 * 64);              // prologue prefetch

  for (int kt = kt0; kt <= qt; ++kt) {
    const int kb = kt * 64;
    // write K/V for this tile (compiler inserts counted vmcnt wait for kreg/vreg; on the
    // first iter the older Q-DMA ops necessarily retire before kreg is available)
#pragma unroll
    for (int i = 0; i < 4; ++i)
      *(bf16x8*)&sK[(size_t)(i*256 + t)*8] = kreg[i];
#pragma unroll
    for (int i = 0; i < 4; ++i)
      *(bf16x8*)&sV[(size_t)(i*256 + t)*8] = vreg[i];
    asm volatile("s_waitcnt lgkmcnt(0)" ::: "memory");
    block_sync();                 // K/V (and Q, 1st iter) visible to all waves
    if (kt < qt) load_kv(kb + 64);  // prefetch next tile under QK+softmax+PV

    // S strip (16 q-rows x 64 k-cols per wave) = Q K^T  (log2-units)
    f32x4 s[4];
#pragma unroll
    for (int nt = 0; nt < 4; ++nt) s[nt] = {0.f, 0.f, 0.f, 0.f};
#pragma unroll
    for (int ds = 0; ds < 4; ++ds) {
      bf16x8 aq = *(const bf16x8*)&sQ[(wave*16 + fm)*128 + (((ds*4 + quad) ^ fsw) << 3)];
#pragma unroll
      for (int nt = 0; nt < 4; ++nt) {
        bf16x8 bk = *(const bf16x8*)&sK[(nt*16 + fm)*128 + (((ds*4 + quad) ^ fsw) << 3)];
        s[nt] = __builtin_amdgcn_mfma_f32_16x16x32_bf16(aq, bk, s[nt], 0, 0, 0);
      }
    }
    block_sync();                 // all waves' QK reads of sK done before P overwrites it

    const bool interior = (kb + 63 <= qw) && (kb >= qw - (WIN_ - 16));
    if (!interior) {
      const int qi0 = qb + wave*16 + quad*4;
#pragma unroll
      for (int nt = 0; nt < 4; ++nt) {
        const int ki = kb + nt*16 + fm;
#pragma unroll
        for (int r = 0; r < 4; ++r) {
          const int qi = qi0 + r;
          const bool ok = (ki <= qi) && (qi - ki < WIN_);
          s[nt][r] = ok ? s[nt][r] : -1e30f;
        }
      }
    }
#pragma unroll
    for (int nt = 0; nt < 4; ++nt)
#pragma unroll
      for (int r = 0; r < 4; ++r) {
        const float p = __builtin_exp2f(s[nt][r]);
        l_run[r] += p;
        sK[(wave*16 + quad*4 + r)*72 + nt*16 + fm] = __float2bfloat16(p);  // P alias
      }
    asm volatile("s_waitcnt lgkmcnt(0)" ::: "memory");
    // O += P V
#pragma unroll
    for (int ks = 0; ks < 2; ++ks) {
      bf16x8 ap = *(const bf16x8*)&sK[(wave*16 + fm)*72 + ks*32 + quad*8];  // P alias
#pragma unroll
      for (int nt = 0; nt < 8; ++nt) {
        bf16x8 bv = *(const bf16x8*)&sV[(nt*16 + fm)*64 + (((ks*4 + quad) ^ fsw) << 3)];
        oacc[nt] = __builtin_amdgcn_mfma_f32_16x16x32_bf16(ap, bv, oacc[nt], 0, 0, 0);
      }
    }
    block_sync();                 // all PV reads of the alias done before next K ds_writes
  }
#pragma unroll
  for (int off = 1; off < 16; off <<= 1)
#pragma unroll
    for (int r = 0; r < 4; ++r) l_run[r] += __shfl_xor(l_run[r], off);
  const float sink_p = __builtin_exp2f(sink[h] * 1.4426950408889634f);
#pragma unroll
  for (int r = 0; r < 4; ++r) {
    const int qi = qb + wave*16 + quad*4 + r;
    const float inv_l = 1.f / (l_run[r] + sink_p);
#pragma unroll
    for (int nt = 0; nt < 8; ++nt) {
      const int d = nt*16 + fm;
      o[(size_t)(b*T_ + qi)*(H_*D_) + h*D_ + d] = __float2bfloat16(oacc[nt][r] * inv_l);
    }
  }
}

// =========================================================================================
extern "C" void kernel_launch(void* const* d_in, const int* in_sizes, int n_in,
                              void* d_out, int out_size, void* d_ws, size_t ws_size,
                              hipStream_t stream) {
  (void)in_sizes; (void)n_in; (void)out_size; (void)ws_size;
  const float* h       = (const float*)d_in[0];
  const float* wq_comp = (const float*)d_in[1];
  const float* wq_up   = (const float*)d_in[2];
  const float* wk      = (const float*)d_in[3];
  const float* wv      = (const float*)d_in[4];
  const float* qnw     = (const float*)d_in[5];
  const float* knw     = (const float*)d_in[6];
  const float* sink    = (const float*)d_in[7];
  const float* w1      = (const float*)d_in[8];
  const float* w2      = (const float*)d_in[9];
  float* out = (float*)d_out;
  bf16* ws   = (bf16*)d_ws;

  // ---- overlaid workspace (bf16 element offsets; peak 35.5M elems = 71 MB) ----
  const size_t M1 = 1048576;
  const size_t o_hb    = 0;               // [4096][2048] ph1-3
  const size_t o_qr    = 8*M1;            // [4096][2048] ph2-4
  const size_t o_w2T   = 0;               // [2048][8192] ph5 (hb,qr dead)
  const size_t o_qkv   = 16*M1;           // [4096][768]  ph2-3 (qc|k|v)
  const size_t o_WefT  = 16*M1;           // [2048][2048] ph5 (qkv dead)
  const size_t o_krt   = 20*M1;           // [4096][128]  ph3-4
  const size_t o_vt    = 20*M1 + 524288;  // [2][128][2048] ph3-4
  const size_t o_wqkvT = 21*M1;           // [768][2048]  ph1-3 (wqcT;wkT;wvT stacked)
  const size_t o_wquT  = 22*M1 + 524288;  // [2048][512]  ph1-2
  const size_t o_w1b   = 23*M1 + 524288;  // [4][512][2048] ph1-5
  const size_t o_x     = 27*M1 + 524288;  // [4096][2048] ph4-5

  const dim3 tb(256);
  // ---- ph1: conversions (merged: 2 launches) ----
  cvt4_all<<<dim3(12288), tb, 0, stream>>>(h, w1, ws+o_hb, ws+o_w1b);
  cvtT_all<<<dim3(2560), tb, 0, stream>>>(wq_comp, wk, wv, wq_up, ws+o_wqkvT, ws+o_wquT);

  // ---- ph2/3: [qc|k|v] = h @ [wqc|wk|wv] in ONE N=768 GEMM (m97 structure) ----
  gemm_bt<false><<<dim3(32, 6), tb, 0, stream>>>(ws+o_hb, ws+o_wqkvT, ws+o_qkv,
                                                 2048, 2048, 2048, 768, 0, 0, 0);
  // q = qc @ wq_up  (8-phase 256x128 pipeline)
  gemm_bt8<false><<<dim3(16, 16), dim3(512), 0, stream>>>(ws+o_qkv, ws+o_wquT, ws+o_qr,
                                                          512, 768, 512, 2048, 0, 0, 0);
  // rope+rms q (pre-scaled by 1/(sqrt(D)ln2)) and k in one launch
  rope_rms_all<<<dim3(17408), tb, 0, stream>>>(ws+o_qr, ws+o_qr, qnw,
                                               ws+o_qkv + 512, ws+o_krt, knw);
  // transpose v -> vt
  transpose_k<<<dim3(4, 64, 2), tb, 0, stream>>>(ws+o_qkv + 640, ws+o_vt, 2048, 128, 768, 2048,
                                                 (long long)2048*768, (long long)128*2048);

  // ---- ph4: attention ----
  attn_kernel<<<dim3(T_/64, H_, B_), tb, 0, stream>>>(ws+o_qr, ws+o_krt, ws+o_vt, sink, ws+o_x);

  // ---- ph5: WeffT = w2T_g @ w1_g^T per group (z=g), then out = x @ WeffT^T ----
  cvtT<<<dim3(64, 256), tb, 0, stream>>>(w2, ws+o_w2T, 8192, 2048);
  gemm_bt8<false><<<dim3(8, 4, 4), dim3(512), 0, stream>>>(ws+o_w2T, ws+o_w1b, ws+o_WefT,
                                                           2048, 8192, 2048, 2048,
                                                           2048, (long long)512*2048, 512);
  gemm_bt8<true><<<dim3(16, 16), dim3(512), 0, stream>>>(ws+o_x, ws+o_WefT, out,
                                                         2048, 2048, 2048, 2048, 0, 0, 0);
}

// Round 4
// 350.003 us; speedup vs baseline: 1.0224x; 1.0126x over previous
//
#include <hip/hip_runtime.h>
#include <hip/hip_bf16.h>
#include <stdint.h>

typedef __hip_bfloat16 bf16;
typedef __bf16 bf16x8 __attribute__((ext_vector_type(8)));
typedef float f32x4 __attribute__((ext_vector_type(4)));

#define B_ 2
#define T_ 2048
#define HID_ 2048
#define H_ 16
#define D_ 128
#define WIN_ 512

// ---- async global->LDS, 16B per lane (lds dest = wave-uniform base + lane*16) ----
__device__ __forceinline__ void async_copy16(const void* g, void* l) {
  __builtin_amdgcn_global_load_lds(
      (__attribute__((address_space(1))) void*)(uintptr_t)g,
      (__attribute__((address_space(3))) void*)(uint32_t)(uintptr_t)l,
      16, 0, 0);
}

// raw workgroup barrier with compiler memory fences (no vmcnt/lgkm drain)
__device__ __forceinline__ void block_sync() {
  asm volatile("" ::: "memory");
  __builtin_amdgcn_s_barrier();
  asm volatile("" ::: "memory");
}

// =================== fused fp32->bf16 (h and w1 in one launch) ===================
__global__ __launch_bounds__(256) void cvt4_all(
    const float* __restrict__ h, const float* __restrict__ w1, bf16* __restrict__ outh, bf16* __restrict__ outw1)
{
  int i = blockIdx.x * 256 + threadIdx.x;
  const int NH = 2097152;            // h: 2*2048*2048 /4
  const float* in; bf16* out;
  if (i < NH) { in = h; out = outh; }
  else { i -= NH; in = w1; out = outw1; }   // w1: 4*512*2048 /4 = 1048576
  const float4 v = ((const float4*)in)[i];
  bf16* p = out + (size_t)i * 4;
  p[0] = __float2bfloat16(v.x);
  p[1] = __float2bfloat16(v.y);
  p[2] = __float2bfloat16(v.z);
  p[3] = __float2bfloat16(v.w);
}

// =================== fused fp32->bf16 + transpose, 4 weight matrices in one launch ===================
// out[C][R] = bf16(in[R][C]^T). Ranges: wq_comp(1024 blk), wk(256), wv(256), wq_up(1024).
__global__ __launch_bounds__(256) void cvtT_all(
    const float* __restrict__ wqc, const float* __restrict__ wk, const float* __restrict__ wv,
    const float* __restrict__ wqu, bf16* __restrict__ qkvT, bf16* __restrict__ wquT)
{
  __shared__ bf16 tile[32][33];
  const int id = blockIdx.x;
  const float* in; bf16* out; int R, C, bx, by;
  if (id < 1024)      { int l = id;        in = wqc; out = qkvT;                      R = 2048; C = 512;  bx = (l & 15) * 32; by = (l >> 4) * 32; }
  else if (id < 1280) { int l = id - 1024; in = wk;  out = qkvT + (size_t)512 * 2048; R = 2048; C = 128;  bx = (l & 3) * 32;  by = (l >> 2) * 32; }
  else if (id < 1536) { int l = id - 1280; in = wv;  out = qkvT + (size_t)640 * 2048; R = 2048; C = 128;  bx = (l & 3) * 32;  by = (l >> 2) * 32; }
  else                { int l = id - 1536; in = wqu; out = wquT;                      R = 512;  C = 2048; bx = (l & 63) * 32; by = (l >> 6) * 32; }
  const int tx = threadIdx.x & 31, ty = threadIdx.x >> 5;
#pragma unroll
  for (int i = 0; i < 32; i += 8)
    tile[ty+i][tx] = __float2bfloat16(in[(size_t)(by + ty + i)*C + bx + tx]);
  __syncthreads();
#pragma unroll
  for (int i = 0; i < 32; i += 8)
    out[(size_t)(bx + ty + i)*R + by + tx] = tile[tx][ty+i];
}

// =================== single fp32->bf16 transpose (w2) ===================
__global__ __launch_bounds__(256) void cvtT(
    const float* __restrict__ in, bf16* __restrict__ out, int R, int C)
{
  __shared__ bf16 tile[32][33];
  const int bx = blockIdx.x*32, by = blockIdx.y*32;
  const int tx = threadIdx.x & 31, ty = threadIdx.x >> 5;
#pragma unroll
  for (int i = 0; i < 32; i += 8)
    tile[ty+i][tx] = __float2bfloat16(in[(size_t)(by + ty + i)*C + bx + tx]);
  __syncthreads();
#pragma unroll
  for (int i = 0; i < 32; i += 8)
    out[(size_t)(bx + ty + i)*R + by + tx] = tile[tx][ty+i];
}

// =================== bf16 transpose: out[C][R] = in[R][C]^T (batched via z) ===================
__global__ __launch_bounds__(256) void transpose_k(
    const bf16* __restrict__ in, bf16* __restrict__ out,
    int R, int C, int ldin, int ldout, long long inBatch, long long outBatch)
{
  __shared__ bf16 tile[32][33];
  in  += (size_t)blockIdx.z * inBatch;
  out += (size_t)blockIdx.z * outBatch;
  const int bx = blockIdx.x*32, by = blockIdx.y*32;
  const int tx = threadIdx.x & 31, ty = threadIdx.x >> 5;
#pragma unroll
  for (int i = 0; i < 32; i += 8)
    tile[ty+i][tx] = in[(size_t)(by + ty + i)*ldin + bx + tx];
  __syncthreads();
#pragma unroll
  for (int i = 0; i < 32; i += 8)
    out[(size_t)(bx + ty + i)*ldout + by + tx] = tile[tx][ty+i];
}

// =================== bf16 GEMM (m97 structure): C[M,N] = A[M,K] * BT[N,K]^T ===================
// kept for the qkv GEMM (N=768 -> 192 blocks; 256x128 tiling would under-occupy)
template <bool F32OUT>
__global__ __launch_bounds__(256) void gemm_bt(
    const bf16* __restrict__ Ab, const bf16* __restrict__ Bb, void* __restrict__ Cb,
    int K, int lda, int ldb, int ldc,
    long long sAz, long long sBz, long long sCz)
{
  const bf16* A = Ab + (size_t)blockIdx.z * sAz;
  const bf16* B = Bb + (size_t)blockIdx.z * sBz;
  __shared__ __align__(16) __bf16 sa[128*64];
  __shared__ __align__(16) __bf16 sb[128*64];
  const int bm = blockIdx.x * 128, bn = blockIdx.y * 128;
  const int t = threadIdx.x;
  const int wave = t >> 6, lane = t & 63;
  const int fm = lane & 15, quad = lane >> 4;
  const int wm = (wave & 1) * 64, wn = (wave >> 1) * 64;
  const int arow0 = t >> 3;
  const int acol_sw = (((t & 7) ^ (arow0 & 7)) << 3);
  const int fsw = fm & 7;

  f32x4 acc[4][4];
#pragma unroll
  for (int i = 0; i < 4; ++i)
#pragma unroll
    for (int j = 0; j < 4; ++j) acc[i][j] = {0.f, 0.f, 0.f, 0.f};

  for (int k0 = 0; k0 < K; k0 += 64) {
    __syncthreads();
#pragma unroll
    for (int i = 0; i < 4; ++i)
      async_copy16(&A[(size_t)(bm + arow0 + i*32)*lda + k0 + acol_sw], &sa[(size_t)(i*256 + wave*64)*8]);
#pragma unroll
    for (int i = 0; i < 4; ++i)
      async_copy16(&B[(size_t)(bn + arow0 + i*32)*ldb + k0 + acol_sw], &sb[(size_t)(i*256 + wave*64)*8]);
    __syncthreads();
#pragma unroll
    for (int ks = 0; ks < 64; ks += 32) {
      bf16x8 av[4], bv[4];
#pragma unroll
      for (int mt = 0; mt < 4; ++mt)
        av[mt] = *(const bf16x8*)&sa[(wm + mt*16 + fm)*64 + ((((ks>>3) + quad) ^ fsw) << 3)];
#pragma unroll
      for (int nt = 0; nt < 4; ++nt)
        bv[nt] = *(const bf16x8*)&sb[(wn + nt*16 + fm)*64 + ((((ks>>3) + quad) ^ fsw) << 3)];
#pragma unroll
      for (int mt = 0; mt < 4; ++mt)
#pragma unroll
        for (int nt = 0; nt < 4; ++nt)
          acc[mt][nt] = __builtin_amdgcn_mfma_f32_16x16x32_bf16(av[mt], bv[nt], acc[mt][nt], 0, 0, 0);
    }
  }
  if constexpr (F32OUT) {
    float* C = (float*)Cb + (size_t)blockIdx.z * sCz;
#pragma unroll
    for (int mt = 0; mt < 4; ++mt)
#pragma unroll
      for (int r = 0; r < 4; ++r) {
        const int row = bm + wm + mt*16 + quad*4 + r;
#pragma unroll
        for (int nt = 0; nt < 4; ++nt)
          C[(size_t)row*ldc + bn + wn + nt*16 + fm] = acc[mt][nt][r];
      }
  } else {
    bf16* C = (bf16*)Cb + (size_t)blockIdx.z * sCz;
#pragma unroll
    for (int mt = 0; mt < 4; ++mt)
#pragma unroll
      for (int r = 0; r < 4; ++r) {
        const int row = bm + wm + mt*16 + quad*4 + r;
#pragma unroll
        for (int nt = 0; nt < 4; ++nt)
          C[(size_t)row*ldc + bn + wn + nt*16 + fm] = __float2bfloat16(acc[mt][nt][r]);
      }
  }
}

// =================== pipelined GEMM v2: 2 phases/K-tile, 16 MFMA/phase ===================
// BM=256, BN=128, BK=64; 512 threads = 8 waves (wave_m 0..3, wave_n 0..1), per-wave 64x64 out.
// Phase 0: ds_read all 8 B-frags + A-frags for q-subtiles {0,1} (12 x b128), issue A(d+1) DMA,
//          barrier, 16 MFMA, barrier.
// Phase 1: ds_read A-frags {2,3}, issue B(d+2) DMA, barrier, 16 MFMA, vmcnt, barrier.
// Hazards: B(d+2) -> sB[par] issued only after p0-end barrier (all waves' B-reads of tile d
// retired before their p0 MFMA); A(d+1) -> sA[par^1]; vmcnt(2) at p1-end retires A(d+1) and
// all older, leaving only B(d+2)'s 2 loads in flight (counted, never 0 in steady state).
template <bool F32OUT>
__global__ __launch_bounds__(512, 2) void gemm_bt8(
    const bf16* __restrict__ Ab, const bf16* __restrict__ Bb, void* __restrict__ Cb,
    int K, int lda, int ldb, int ldc,
    long long sAz, long long sBz, long long sCz)
{
  const bf16* A = Ab + (size_t)blockIdx.z * sAz;
  const bf16* B = Bb + (size_t)blockIdx.z * sBz;
  __shared__ __align__(16) __bf16 sA[2][256*64];
  __shared__ __align__(16) __bf16 sB[2][128*64];
  const int bm = blockIdx.x * 256, bn = blockIdx.y * 128;
  const int t = threadIdx.x;
  const int wave = t >> 6, lane = t & 63;
  const int fm = lane & 15, quad = lane >> 4, fsw = fm & 7;
  const int wave_m = wave >> 1, wave_n = wave & 1;
  const int srow = t >> 3;                      // staging row within a 64-row granule
  const int cchunk = (t & 7) ^ (srow & 7);      // pre-swizzled source chunk (inverse of read XOR)
  const int NT = K >> 6;                        // number of K-tiles (NT >= 2 required)

  auto stage = [&](int tile, int o) {           // o: 0=Bh0 1=Bh1 2=Ah0 3=Ah1
    if (tile >= NT) return;
    const int par = tile & 1;
    const int kc = (tile << 6) + (cchunk << 3);
    if (o < 2) {
      async_copy16(&B[(size_t)(bn + (o << 6) + srow)*ldb + kc],
                   &sB[par][(size_t)((o << 6) + wave*8) * 64]);
    } else {
      const int h = (o - 2) << 7;
      async_copy16(&A[(size_t)(bm + h + srow)*lda + kc],
                   &sA[par][(size_t)(h + wave*8) * 64]);
      async_copy16(&A[(size_t)(bm + h + 64 + srow)*lda + kc],
                   &sA[par][(size_t)(h + 64 + wave*8) * 64]);
    }
  };

  f32x4 acc[4][4];
#pragma unroll
  for (int i = 0; i < 4; ++i)
#pragma unroll
    for (int j = 0; j < 4; ++j) acc[i][j] = {0.f, 0.f, 0.f, 0.f};

  // prologue: A(0) 4, B(0) 2 (oldest 6), then B(1) 2; vmcnt(2) leaves B(1) in flight
  stage(0, 2); stage(0, 3); stage(0, 0); stage(0, 1);
  stage(1, 0); stage(1, 1);
  asm volatile("s_waitcnt vmcnt(2)" ::: "memory");
  block_sync();

  for (int d = 0; d < NT; ++d) {
    const int par = d & 1;
    bf16x8 bfr[4][2], a01[2][2], a23[2][2];
    // ---------------- phase 0: q-subtiles 0,1 ----------------
#pragma unroll
    for (int n = 0; n < 4; ++n) {
      const int brow = wave_n*64 + n*16 + fm;
      bfr[n][0] = *(const bf16x8*)&sB[par][(size_t)brow*64 + ((quad ^ fsw) << 3)];
      bfr[n][1] = *(const bf16x8*)&sB[par][(size_t)brow*64 + (((4 + quad) ^ fsw) << 3)];
    }
#pragma unroll
    for (int qq = 0; qq < 2; ++qq) {
      const int arow = wave_m*64 + qq*16 + fm;
      a01[qq][0] = *(const bf16x8*)&sA[par][(size_t)arow*64 + ((quad ^ fsw) << 3)];
      a01[qq][1] = *(const bf16x8*)&sA[par][(size_t)arow*64 + (((4 + quad) ^ fsw) << 3)];
    }
    stage(d + 1, 2); stage(d + 1, 3);
    block_sync();
    __builtin_amdgcn_s_setprio(1);
#pragma unroll
    for (int qq = 0; qq < 2; ++qq)
#pragma unroll
      for (int n = 0; n < 4; ++n) {
        acc[qq][n] = __builtin_amdgcn_mfma_f32_16x16x32_bf16(a01[qq][0], bfr[n][0], acc[qq][n], 0, 0, 0);
        acc[qq][n] = __builtin_amdgcn_mfma_f32_16x16x32_bf16(a01[qq][1], bfr[n][1], acc[qq][n], 0, 0, 0);
      }
    __builtin_amdgcn_s_setprio(0);
    block_sync();
    // ---------------- phase 1: q-subtiles 2,3 ----------------
#pragma unroll
    for (int qq = 0; qq < 2; ++qq) {
      const int arow = wave_m*64 + (2 + qq)*16 + fm;
      a23[qq][0] = *(const bf16x8*)&sA[par][(size_t)arow*64 + ((quad ^ fsw) << 3)];
      a23[qq][1] = *(const bf16x8*)&sA[par][(size_t)arow*64 + (((4 + quad) ^ fsw) << 3)];
    }
    stage(d + 2, 0); stage(d + 2, 1);
    block_sync();
    __builtin_amdgcn_s_setprio(1);
#pragma unroll
    for (int qq = 0; qq < 2; ++qq)
#pragma unroll
      for (int n = 0; n < 4; ++n) {
        acc[2+qq][n] = __builtin_amdgcn_mfma_f32_16x16x32_bf16(a23[qq][0], bfr[n][0], acc[2+qq][n], 0, 0, 0);
        acc[2+qq][n] = __builtin_amdgcn_mfma_f32_16x16x32_bf16(a23[qq][1], bfr[n][1], acc[2+qq][n], 0, 0, 0);
      }
    __builtin_amdgcn_s_setprio(0);
    if (d < NT - 1) {                     // per-K-tile checkpoint guarding tile d+1
      if (d == NT - 2) asm volatile("s_waitcnt vmcnt(0)" ::: "memory");
      else             asm volatile("s_waitcnt vmcnt(2)" ::: "memory");
    }
    block_sync();
  }

  if constexpr (F32OUT) {
    float* C = (float*)Cb + (size_t)blockIdx.z * sCz;
#pragma unroll
    for (int q = 0; q < 4; ++q)
#pragma unroll
      for (int r = 0; r < 4; ++r) {
        const int row = bm + wave_m*64 + q*16 + quad*4 + r;
#pragma unroll
        for (int n = 0; n < 4; ++n)
          C[(size_t)row*ldc + bn + wave_n*64 + n*16 + fm] = acc[q][n][r];
      }
  } else {
    bf16* C = (bf16*)Cb + (size_t)blockIdx.z * sCz;
#pragma unroll
    for (int q = 0; q < 4; ++q)
#pragma unroll
      for (int r = 0; r < 4; ++r) {
        const int row = bm + wave_m*64 + q*16 + quad*4 + r;
#pragma unroll
        for (int n = 0; n < 4; ++n)
          C[(size_t)row*ldc + bn + wave_n*64 + n*16 + fm] = __float2bfloat16(acc[q][n][r]);
      }
  }
}

// =================== fused partial-RoPE + RMSNorm, q and k paths in one launch ===================
__global__ __launch_bounds__(256) void rope_rms_all(
    const bf16* __restrict__ qin, bf16* __restrict__ qout, const float* __restrict__ qw,
    const bf16* __restrict__ kin, bf16* __restrict__ kout, const float* __restrict__ kw)
{
  int blk = blockIdx.x;
  const bf16* in; bf16* out; const float* w; int in_stride, t_shift; float oscale;
  if (blk < 16384) { in = qin; out = qout; w = qw; in_stride = 128; t_shift = 4; oscale = 0.12751744f; }
  else { blk -= 16384; in = kin; out = kout; w = kw; in_stride = 768; t_shift = 0; oscale = 1.0f; }
  const int rid = blk*4 + (threadIdx.x >> 6);
  const int lane = threadIdx.x & 63;
  const bf16* row = in + (size_t)rid * in_stride;
  float e0 = __bfloat162float(row[lane]);
  float e1 = __bfloat162float(row[lane + 64]);
  float s2 = e0*e0 + e1*e1;
#pragma unroll
  for (int off = 32; off; off >>= 1) s2 += __shfl_xor(s2, off);
  const float rms = rsqrtf(s2 * (1.f/128.f) + 1e-6f) * oscale;
  const int tpos = (rid >> t_shift) & (T_ - 1);
  const int i = lane & 31;
  const float inv = expf(-(float)i * 0.28782313662425574f);  // ln(10000)/32
  const float ang = (float)tpos * inv;
  float sn, c;
  sincosf(ang, &sn, &c);
  const float other = __shfl_xor(e0, 32);
  const float r0 = (lane < 32) ? (e0*c - other*sn) : (other*sn + e0*c);
  bf16* orow = out + (size_t)rid * 128;
  orow[lane]      = __float2bfloat16(r0 * rms * w[lane]);
  orow[lane + 64] = __float2bfloat16(e1 * rms * w[lane + 64]);
}

// =================== sliding-window flash attention (MQA, sink, max-free, swizzled LDS) ===================
// Swapped QK^T (T12-style): s = mfma(K,Q) puts P[q=fm][k=nt*16+quad*4+r] lane-local in q, so
// the P->LDS spill is 8 cvt_pk + 4 ds_write_b64 instead of 16 scalar cvt + 16 ds_write_b16.
// l becomes a lane scalar (reduced across quads once at the end). PV path/oacc layout unchanged.
// P aliases into sK (dead after QK) for 49152 B LDS -> 3 blocks/CU. T14 reg-staged K/V prefetch.
__global__ __launch_bounds__(256, 3) void attn_kernel(
    const bf16* __restrict__ q,     // [B,T,H*D]  (pre-scaled by 1/(sqrt(D)ln2))
    const bf16* __restrict__ k,     // [B,T,D]
    const bf16* __restrict__ vt,    // [B,D,T]
    const float* __restrict__ sink, // [H]
    bf16* __restrict__ o)           // [B,T,H*D]
{
  __shared__ __align__(16) __bf16 sQ[64*128];   // 16 chunk-slots/row, swizzled ^(r&7)
  __shared__ __align__(16) __bf16 sK[64*128];   // post-QK: first 64*72 elems reused as P
  __shared__ __align__(16) __bf16 sV[128*64];   // [d][s], 8 slots/row, swizzled ^(d&7)
  const int qt = blockIdx.x, h = blockIdx.y, b = blockIdx.z;
  const int qb = qt * 64;
  const int t = threadIdx.x, wave = t >> 6, lane = t & 63;
  const int fm = lane & 15, quad = lane >> 4;
  const int fsw = fm & 7;
  const int qw = qb + wave*16;

#pragma unroll
  for (int i = 0; i < 4; ++i) {   // stage Q once (async, source-swizzled)
    int chunk = i*256 + t;
    int r = chunk >> 4, c8 = (chunk & 15) ^ (r & 7);
    async_copy16(&q[(size_t)((b*T_ + qb + r)*H_ + h)*D_ + c8*8], &sQ[(size_t)(i*256 + wave*64)*8]);
  }

  bf16x8 kreg[4], vreg[4];
  auto load_kv = [&](int kb) {     // source-swizzled (same layout the DMA produced)
#pragma unroll
    for (int i = 0; i < 4; ++i) {
      int chunk = i*256 + t;
      int r = chunk >> 4, c8 = (chunk & 15) ^ (r & 7);
      kreg[i] = *(const bf16x8*)&k[(size_t)(b*T_ + kb + r)*D_ + c8*8];
    }
#pragma unroll
    for (int i = 0; i < 4; ++i) {
      int chunk = i*256 + t;
      int d = chunk >> 3, c8 = (chunk & 7) ^ (d & 7);
      vreg[i] = *(const bf16x8*)&vt[(size_t)(b*D_ + d)*T_ + kb + c8*8];
    }
  };

  float l_part = 0.f;             // partial softmax denom for q = qb + wave*16 + fm
  f32x4 oacc[8];
#pragma unroll
  for (int i = 0; i < 8; ++i) oacc[i] = {0.f, 0.f, 0.f, 0.f};

  int lo = qb - (WIN_ - 1); if (lo < 0) lo = 0;
  const int kt0 = lo >> 6;
  load_kv(kt0 * 64);              // prologue prefetch

  for (int kt = kt0; kt <= qt; ++kt) {
    const int kb = kt * 64;
    // write K/V for this tile (compiler inserts counted vmcnt wait for kreg/vreg; on the
    // first iter the older Q-DMA ops necessarily retire before kreg is available)
#pragma unroll
    for (int i = 0; i < 4; ++i)
      *(bf16x8*)&sK[(size_t)(i*256 + t)*8] = kreg[i];
#pragma unroll
    for (int i = 0; i < 4; ++i)
      *(bf16x8*)&sV[(size_t)(i*256 + t)*8] = vreg[i];
    asm volatile("s_waitcnt lgkmcnt(0)" ::: "memory");
    block_sync();                 // K/V (and Q, 1st iter) visible to all waves
    if (kt < qt) load_kv(kb + 64);  // prefetch next tile under QK+softmax+PV

    // S^T strip: s[nt][r] = S[k = kb+nt*16+quad*4+r][q = qb+wave*16+fm]  (swapped operands)
    f32x4 s[4];
#pragma unroll
    for (int nt = 0; nt < 4; ++nt) s[nt] = {0.f, 0.f, 0.f, 0.f};
#pragma unroll
    for (int ds = 0; ds < 4; ++ds) {
      bf16x8 aq = *(const bf16x8*)&sQ[(wave*16 + fm)*128 + (((ds*4 + quad) ^ fsw) << 3)];
#pragma unroll
      for (int nt = 0; nt < 4; ++nt) {
        bf16x8 bk = *(const bf16x8*)&sK[(nt*16 + fm)*128 + (((ds*4 + quad) ^ fsw) << 3)];
        s[nt] = __builtin_amdgcn_mfma_f32_16x16x32_bf16(bk, aq, s[nt], 0, 0, 0);  // SWAPPED
      }
    }
    block_sync();                 // all waves' QK reads of sK done before P overwrites it

    const bool interior = (kb + 63 <= qw) && (kb >= qw - (WIN_ - 16));
    if (!interior) {
      const int qi = qb + wave*16 + fm;
#pragma unroll
      for (int nt = 0; nt < 4; ++nt)
#pragma unroll
        for (int r = 0; r < 4; ++r) {
          const int ki = kb + nt*16 + quad*4 + r;
          const bool ok = (ki <= qi) && (qi - ki < WIN_);
          s[nt][r] = ok ? s[nt][r] : -1e30f;
        }
    }
#pragma unroll
    for (int nt = 0; nt < 4; ++nt)
#pragma unroll
      for (int r = 0; r < 4; ++r) {
        s[nt][r] = __builtin_exp2f(s[nt][r]);
        l_part += s[nt][r];
      }
    // packed P-write: row q (wave-private), cols nt*16 + quad*4 + {0..3}
#pragma unroll
    for (int nt = 0; nt < 4; ++nt) {
      uint32_t plo, phi;
      asm("v_cvt_pk_bf16_f32 %0, %1, %2" : "=v"(plo) : "v"(s[nt][0]), "v"(s[nt][1]));
      asm("v_cvt_pk_bf16_f32 %0, %1, %2" : "=v"(phi) : "v"(s[nt][2]), "v"(s[nt][3]));
      uint2 pw; pw.x = plo; pw.y = phi;
      *(uint2*)&sK[(wave*16 + fm)*72 + nt*16 + quad*4] = pw;
    }
    asm volatile("s_waitcnt lgkmcnt(0)" ::: "memory");
    // O += P V  (ap reads wave-private P rows; layout identical to pre-swap version)
#pragma unroll
    for (int ks = 0; ks < 2; ++ks) {
      bf16x8 ap = *(const bf16x8*)&sK[(wave*16 + fm)*72 + ks*32 + quad*8];  // P alias
#pragma unroll
      for (int nt = 0; nt < 8; ++nt) {
        bf16x8 bv = *(const bf16x8*)&sV[(nt*16 + fm)*64 + (((ks*4 + quad) ^ fsw) << 3)];
        oacc[nt] = __builtin_amdgcn_mfma_f32_16x16x32_bf16(ap, bv, oacc[nt], 0, 0, 0);
      }
    }
    block_sync();                 // all PV reads of the alias done before next K ds_writes
  }
  // reduce l across quads (lanes with same fm), then redistribute to output rows
  l_part += __shfl_xor(l_part, 16);
  l_part += __shfl_xor(l_part, 32);   // now l_part = L[q = qb + wave*16 + fm]
  const float sink_p = __builtin_exp2f(sink[h] * 1.4426950408889634f);
#pragma unroll
  for (int r = 0; r < 4; ++r) {
    const int qi = qb + wave*16 + quad*4 + r;
    const float inv_l = 1.f / (__shfl(l_part, quad*4 + r) + sink_p);
#pragma unroll
    for (int nt = 0; nt < 8; ++nt) {
      const int d = nt*16 + fm;
      o[(size_t)(b*T_ + qi)*(H_*D_) + h*D_ + d] = __float2bfloat16(oacc[nt][r] * inv_l);
    }
  }
}

// =========================================================================================
extern "C" void kernel_launch(void* const* d_in, const int* in_sizes, int n_in,
                              void* d_out, int out_size, void* d_ws, size_t ws_size,
                              hipStream_t stream) {
  (void)in_sizes; (void)n_in; (void)out_size; (void)ws_size;
  const float* h       = (const float*)d_in[0];
  const float* wq_comp = (const float*)d_in[1];
  const float* wq_up   = (const float*)d_in[2];
  const float* wk      = (const float*)d_in[3];
  const float* wv      = (const float*)d_in[4];
  const float* qnw     = (const float*)d_in[5];
  const float* knw     = (const float*)d_in[6];
  const float* sink    = (const float*)d_in[7];
  const float* w1      = (const float*)d_in[8];
  const float* w2      = (const float*)d_in[9];
  float* out = (float*)d_out;
  bf16* ws   = (bf16*)d_ws;

  // ---- overlaid workspace (bf16 element offsets; peak 35.5M elems = 71 MB) ----
  const size_t M1 = 1048576;
  const size_t o_hb    = 0;               // [4096][2048] ph1-3
  const size_t o_qr    = 8*M1;            // [4096][2048] ph2-4
  const size_t o_w2T   = 0;               // [2048][8192] ph5 (hb,qr dead)
  const size_t o_qkv   = 16*M1;           // [4096][768]  ph2-3 (qc|k|v)
  const size_t o_WefT  = 16*M1;           // [2048][2048] ph5 (qkv dead)
  const size_t o_krt   = 20*M1;           // [4096][128]  ph3-4
  const size_t o_vt    = 20*M1 + 524288;  // [2][128][2048] ph3-4
  const size_t o_wqkvT = 21*M1;           // [768][2048]  ph1-3 (wqcT;wkT;wvT stacked)
  const size_t o_wquT  = 22*M1 + 524288;  // [2048][512]  ph1-2
  const size_t o_w1b   = 23*M1 + 524288;  // [4][512][2048] ph1-5
  const size_t o_x     = 27*M1 + 524288;  // [4096][2048] ph4-5

  const dim3 tb(256);
  // ---- ph1: conversions (merged: 2 launches) ----
  cvt4_all<<<dim3(12288), tb, 0, stream>>>(h, w1, ws+o_hb, ws+o_w1b);
  cvtT_all<<<dim3(2560), tb, 0, stream>>>(wq_comp, wk, wv, wq_up, ws+o_wqkvT, ws+o_wquT);

  // ---- ph2/3: [qc|k|v] = h @ [wqc|wk|wv] in ONE N=768 GEMM (m97 structure) ----
  gemm_bt<false><<<dim3(32, 6), tb, 0, stream>>>(ws+o_hb, ws+o_wqkvT, ws+o_qkv,
                                                 2048, 2048, 2048, 768, 0, 0, 0);
  // q = qc @ wq_up  (2-phase x 16-MFMA pipeline)
  gemm_bt8<false><<<dim3(16, 16), dim3(512), 0, stream>>>(ws+o_qkv, ws+o_wquT, ws+o_qr,
                                                          512, 768, 512, 2048, 0, 0, 0);
  // rope+rms q (pre-scaled by 1/(sqrt(D)ln2)) and k in one launch
  rope_rms_all<<<dim3(17408), tb, 0, stream>>>(ws+o_qr, ws+o_qr, qnw,
                                               ws+o_qkv + 512, ws+o_krt, knw);
  // transpose v -> vt
  transpose_k<<<dim3(4, 64, 2), tb, 0, stream>>>(ws+o_qkv + 640, ws+o_vt, 2048, 128, 768, 2048,
                                                 (long long)2048*768, (long long)128*2048);

  // ---- ph4: attention ----
  attn_kernel<<<dim3(T_/64, H_, B_), tb, 0, stream>>>(ws+o_qr, ws+o_krt, ws+o_vt, sink, ws+o_x);

  // ---- ph5: WeffT = w2T_g @ w1_g^T per group (z=g), then out = x @ WeffT^T ----
  cvtT<<<dim3(64, 256), tb, 0, stream>>>(w2, ws+o_w2T, 8192, 2048);
  gemm_bt8<false><<<dim3(8, 4, 4), dim3(512), 0, stream>>>(ws+o_w2T, ws+o_w1b, ws+o_WefT,
                                                           2048, 8192, 2048, 2048,
                                                           2048, (long long)512*2048, 512);
  gemm_bt8<true><<<dim3(16, 16), dim3(512), 0, stream>>>(ws+o_x, ws+o_WefT, out,
                                                         2048, 2048, 2048, 2048, 0, 0, 0);
}